// Round 1
// baseline (2195.398 us; speedup 1.0000x reference)
//
#include <hip/hip_runtime.h>
#include <math.h>

#define TT  1024
#define DD  2048
#define NHH 2048
#define CC  1000

// ---------------------------------------------------------------------------
// init: write epoch-0 tagged H (hprev0) into slot 0 of the 4-slot H buffer.
// Tag = hi 32 bits (epoch), value = lo 32 bits (f32 bits). ws poison 0xAA..
// never matches a real epoch, so unwritten slots simply cause retries.
// ---------------------------------------------------------------------------
__global__ void k_init(const float* __restrict__ hp0, unsigned long long* __restrict__ Hbuf) {
    int i = blockIdx.x * blockDim.x + threadIdx.x;
    if (i < NHH) Hbuf[i] = (unsigned long long)__float_as_uint(hp0[i]); // tag 0
}

// ---------------------------------------------------------------------------
// GEMM: XH = x @ Wh^T ; XZ = x @ Wz^T + bz   (fp32, 64x64 tile, BK=32)
// grid (NHH/64, TT/64, 2); z=0 -> Wh/XH, z=1 -> Wz/XZ+bias
// ---------------------------------------------------------------------------
__global__ __launch_bounds__(256) void k_gemm(const float* __restrict__ X,
                                              const float* __restrict__ Wh,
                                              const float* __restrict__ Wz,
                                              const float* __restrict__ bz,
                                              float* __restrict__ XH,
                                              float* __restrict__ XZ) {
    __shared__ float As[32][68];   // [k][m], pad 68 (16B-aligned rows, odd-ish banks)
    __shared__ float Bs[32][68];   // [k][n]
    const int z = blockIdx.z;
    const float* __restrict__ W = z ? Wz : Wh;
    float* __restrict__ OUT = z ? XZ : XH;
    const int n0 = blockIdx.x * 64;
    const int m0 = blockIdx.y * 64;
    const int tid = threadIdx.x;
    const int tx = tid & 15, ty = tid >> 4;
    const int lr = tid >> 2;           // 0..63 row within tile
    const int lc = (tid & 3) * 8;      // 0,8,16,24 col base

    float acc[4][4] = {};
    for (int k0 = 0; k0 < DD; k0 += 32) {
        float4 a0 = *(const float4*)&X[(size_t)(m0 + lr) * DD + k0 + lc];
        float4 a1 = *(const float4*)&X[(size_t)(m0 + lr) * DD + k0 + lc + 4];
        float4 b0 = *(const float4*)&W[(size_t)(n0 + lr) * DD + k0 + lc];
        float4 b1 = *(const float4*)&W[(size_t)(n0 + lr) * DD + k0 + lc + 4];
        As[lc+0][lr]=a0.x; As[lc+1][lr]=a0.y; As[lc+2][lr]=a0.z; As[lc+3][lr]=a0.w;
        As[lc+4][lr]=a1.x; As[lc+5][lr]=a1.y; As[lc+6][lr]=a1.z; As[lc+7][lr]=a1.w;
        Bs[lc+0][lr]=b0.x; Bs[lc+1][lr]=b0.y; Bs[lc+2][lr]=b0.z; Bs[lc+3][lr]=b0.w;
        Bs[lc+4][lr]=b1.x; Bs[lc+5][lr]=b1.y; Bs[lc+6][lr]=b1.z; Bs[lc+7][lr]=b1.w;
        __syncthreads();
#pragma unroll
        for (int kk = 0; kk < 32; ++kk) {
            float4 av = *(const float4*)&As[kk][ty * 4];
            float4 bv = *(const float4*)&Bs[kk][tx * 4];
            acc[0][0] = fmaf(av.x, bv.x, acc[0][0]); acc[0][1] = fmaf(av.x, bv.y, acc[0][1]);
            acc[0][2] = fmaf(av.x, bv.z, acc[0][2]); acc[0][3] = fmaf(av.x, bv.w, acc[0][3]);
            acc[1][0] = fmaf(av.y, bv.x, acc[1][0]); acc[1][1] = fmaf(av.y, bv.y, acc[1][1]);
            acc[1][2] = fmaf(av.y, bv.z, acc[1][2]); acc[1][3] = fmaf(av.y, bv.w, acc[1][3]);
            acc[2][0] = fmaf(av.z, bv.x, acc[2][0]); acc[2][1] = fmaf(av.z, bv.y, acc[2][1]);
            acc[2][2] = fmaf(av.z, bv.z, acc[2][2]); acc[2][3] = fmaf(av.z, bv.w, acc[2][3]);
            acc[3][0] = fmaf(av.w, bv.x, acc[3][0]); acc[3][1] = fmaf(av.w, bv.y, acc[3][1]);
            acc[3][2] = fmaf(av.w, bv.z, acc[3][2]); acc[3][3] = fmaf(av.w, bv.w, acc[3][3]);
        }
        __syncthreads();
    }
    float4 bias = make_float4(0.f, 0.f, 0.f, 0.f);
    if (z) bias = *(const float4*)&bz[n0 + tx * 4];
#pragma unroll
    for (int i = 0; i < 4; ++i) {
        float4 o = make_float4(acc[i][0] + bias.x, acc[i][1] + bias.y,
                               acc[i][2] + bias.z, acc[i][3] + bias.w);
        *(float4*)&OUT[(size_t)(m0 + ty * 4 + i) * NHH + n0 + tx * 4] = o;
    }
}

// ---------------------------------------------------------------------------
// Recurrent scan: 256 WGs (1/CU) x 256 threads. WG wg owns h-elements
// [8*wg, 8*wg+8): Uz rows (waves 0,1) and Uh rows (waves 2,3), 4 rows/wave,
// 32 U-elements/lane/row held in REGISTERS (128 VGPR/lane).
// Epoch exchange: 4-slot tagged (epoch<<32 | f32bits) buffer, relaxed
// agent-scope 64-bit atomics, publish-early. No grid barrier.
// ---------------------------------------------------------------------------
__global__ __launch_bounds__(256, 2) void k_recur(
    const float* __restrict__ XH, const float* __restrict__ XZ,
    const float* __restrict__ Uh, const float* __restrict__ Uz,
    const float* __restrict__ zt0, const float* __restrict__ ht0,
    const float* __restrict__ hp0,
    unsigned long long* __restrict__ Hbuf) {
    __shared__ float Hs[NHH];
    __shared__ float zt_s[8], ht_s[8], hpr_s[8], dot_s[16];
    const int tid  = threadIdx.x;
    const int wave = tid >> 6, lane = tid & 63;
    const int base8 = blockIdx.x * 8;

    // load this wave's 4 U rows into registers: u[r][c*4+q] = U[row][c*256+lane*4+q]
    const float* __restrict__ Um = (wave < 2) ? Uz : Uh;
    const int r0 = base8 + (wave & 1) * 4;
    float u[4][32];
#pragma unroll
    for (int r = 0; r < 4; ++r) {
        const float* __restrict__ row = Um + (size_t)(r0 + r) * NHH;
#pragma unroll
        for (int c = 0; c < 8; ++c) {
            float4 v = *(const float4*)&row[c * 256 + lane * 4];
            u[r][c*4+0] = v.x; u[r][c*4+1] = v.y; u[r][c*4+2] = v.z; u[r][c*4+3] = v.w;
        }
    }
    if (tid < 8) {
        zt_s[tid]  = zt0[base8 + tid];
        ht_s[tid]  = ht0[base8 + tid];
        hpr_s[tid] = hp0[base8 + tid];
    }
    __syncthreads();

    float xzv = 0.f, xhv = 0.f;
    for (int t = 0; t < TT; ++t) {
        // (A) publish epoch t+1 from stale state; prefetch this step's xz/xh
        if (tid < 8) {
            float zt = zt_s[tid], ht = ht_s[tid], hp = hpr_s[tid];
            float hnew = (1.0f - zt) * hp + zt * ht;
            hpr_s[tid] = hnew;
            unsigned long long pr = ((unsigned long long)(unsigned)(t + 1) << 32)
                                  | (unsigned long long)__float_as_uint(hnew);
            __hip_atomic_store(&Hbuf[(size_t)((t + 1) & 3) * NHH + base8 + tid], pr,
                               __ATOMIC_RELAXED, __HIP_MEMORY_SCOPE_AGENT);
            xzv = XZ[(size_t)t * NHH + base8 + tid];
            xhv = XH[(size_t)t * NHH + base8 + tid];
        }
        // (B) gather full epoch-t H into LDS (issue all 8, then fix stale)
        const unsigned long long* __restrict__ src = Hbuf + (size_t)(t & 3) * NHH;
        unsigned long long pv[8];
#pragma unroll
        for (int k = 0; k < 8; ++k)
            pv[k] = __hip_atomic_load(&src[k * 256 + tid], __ATOMIC_RELAXED, __HIP_MEMORY_SCOPE_AGENT);
#pragma unroll
        for (int k = 0; k < 8; ++k) {
            while ((unsigned)(pv[k] >> 32) != (unsigned)t) {
                __builtin_amdgcn_s_sleep(1);
                pv[k] = __hip_atomic_load(&src[k * 256 + tid], __ATOMIC_RELAXED, __HIP_MEMORY_SCOPE_AGENT);
            }
            Hs[k * 256 + tid] = __uint_as_float((unsigned)pv[k]);
        }
        __syncthreads();
        // (D) matvec: 4 rows/wave from register-resident U
        float a0 = 0.f, a1 = 0.f, a2 = 0.f, a3 = 0.f;
#pragma unroll
        for (int c = 0; c < 8; ++c) {
            float4 h4 = *(const float4*)&Hs[c * 256 + lane * 4];
            a0 = fmaf(u[0][c*4+0], h4.x, fmaf(u[0][c*4+1], h4.y, fmaf(u[0][c*4+2], h4.z, fmaf(u[0][c*4+3], h4.w, a0))));
            a1 = fmaf(u[1][c*4+0], h4.x, fmaf(u[1][c*4+1], h4.y, fmaf(u[1][c*4+2], h4.z, fmaf(u[1][c*4+3], h4.w, a1))));
            a2 = fmaf(u[2][c*4+0], h4.x, fmaf(u[2][c*4+1], h4.y, fmaf(u[2][c*4+2], h4.z, fmaf(u[2][c*4+3], h4.w, a2))));
            a3 = fmaf(u[3][c*4+0], h4.x, fmaf(u[3][c*4+1], h4.y, fmaf(u[3][c*4+2], h4.z, fmaf(u[3][c*4+3], h4.w, a3))));
        }
#pragma unroll
        for (int off = 32; off > 0; off >>= 1) {
            a0 += __shfl_xor(a0, off);
            a1 += __shfl_xor(a1, off);
            a2 += __shfl_xor(a2, off);
            a3 += __shfl_xor(a3, off);
        }
        if (lane == 0) {
            int di = ((wave & 1) * 4) + ((wave >> 1) * 8); // Uz dots -> 0..7, Uh -> 8..15
            dot_s[di + 0] = a0; dot_s[di + 1] = a1; dot_s[di + 2] = a2; dot_s[di + 3] = a3;
        }
        __syncthreads();
        // (F) refresh gates from OLD hprev's matvec (reference order)
        if (tid < 8) {
            zt_s[tid] = 1.0f / (1.0f + expf(-(xzv + dot_s[tid])));
            ht_s[tid] = tanhf(xhv + dot_s[8 + tid]);
        }
        __syncthreads();
    }
}

// ---------------------------------------------------------------------------
// logits[r] = Wout[r,:] . H_final   (H_final = epoch 1024 -> slot 0)
// ---------------------------------------------------------------------------
__global__ __launch_bounds__(256) void k_logits(const unsigned long long* __restrict__ Hbuf,
                                                const float* __restrict__ Wout,
                                                float* __restrict__ lg) {
    __shared__ float Hs[NHH];
    const int tid = threadIdx.x;
    for (int k = tid; k < NHH; k += 256) Hs[k] = __uint_as_float((unsigned)Hbuf[k]);
    __syncthreads();
    const int wave = tid >> 6, lane = tid & 63;
    const int row = blockIdx.x * 4 + wave;
    float a = 0.f;
#pragma unroll
    for (int c = 0; c < 8; ++c) {
        float4 w = *(const float4*)&Wout[(size_t)row * NHH + c * 256 + lane * 4];
        float4 h = *(const float4*)&Hs[c * 256 + lane * 4];
        a = fmaf(w.x, h.x, fmaf(w.y, h.y, fmaf(w.z, h.z, fmaf(w.w, h.w, a))));
    }
#pragma unroll
    for (int off = 32; off > 0; off >>= 1) a += __shfl_xor(a, off);
    if (lane == 0) lg[row] = a;
}

// ---------------------------------------------------------------------------
// softmax over 1000 logits, single block
// ---------------------------------------------------------------------------
__global__ __launch_bounds__(1024) void k_softmax(const float* __restrict__ lg,
                                                  float* __restrict__ out) {
    const int i = threadIdx.x;
    __shared__ float red[16];
    __shared__ float bc[2];
    float v = (i < CC) ? lg[i] : -3.0e38f;
    float m = v;
#pragma unroll
    for (int off = 32; off > 0; off >>= 1) m = fmaxf(m, __shfl_xor(m, off));
    if ((i & 63) == 0) red[i >> 6] = m;
    __syncthreads();
    if (i == 0) { float mm = red[0]; for (int k = 1; k < 16; ++k) mm = fmaxf(mm, red[k]); bc[0] = mm; }
    __syncthreads();
    float e = (i < CC) ? expf(v - bc[0]) : 0.f;
    float s = e;
#pragma unroll
    for (int off = 32; off > 0; off >>= 1) s += __shfl_xor(s, off);
    if ((i & 63) == 0) red[i >> 6] = s;
    __syncthreads();
    if (i == 0) { float ss = 0.f; for (int k = 0; k < 16; ++k) ss += red[k]; bc[1] = ss; }
    __syncthreads();
    if (i < CC) out[i] = e / bc[1];
}

extern "C" void kernel_launch(void* const* d_in, const int* in_sizes, int n_in,
                              void* d_out, int out_size, void* d_ws, size_t ws_size,
                              hipStream_t stream) {
    const float* x    = (const float*)d_in[0];
    const float* Wh   = (const float*)d_in[1];
    const float* Wz   = (const float*)d_in[2];
    // d_in[3] = Wr  (dead code in reference)
    const float* Uh   = (const float*)d_in[4];
    const float* Uz   = (const float*)d_in[5];
    const float* bz   = (const float*)d_in[6];
    // d_in[7] = Ur, d_in[8] = br (dead code)
    const float* Wout = (const float*)d_in[9];
    // d_in[10] = h0 (overwritten before use since T>=1)
    const float* zt0  = (const float*)d_in[11];
    const float* ht0  = (const float*)d_in[12];
    const float* hp0  = (const float*)d_in[13];
    float* out = (float*)d_out;

    float* XH = (float*)d_ws;                                   // T*NH f32
    float* XZ = XH + (size_t)TT * NHH;                          // T*NH f32
    unsigned long long* Hbuf = (unsigned long long*)(XZ + (size_t)TT * NHH); // 4*NH u64
    float* lg = (float*)(Hbuf + 4 * NHH);                       // CC f32

    k_init<<<dim3((NHH + 255) / 256), dim3(256), 0, stream>>>(hp0, Hbuf);
    k_gemm<<<dim3(NHH / 64, TT / 64, 2), dim3(256), 0, stream>>>(x, Wh, Wz, bz, XH, XZ);
    k_recur<<<dim3(256), dim3(256), 0, stream>>>(XH, XZ, Uh, Uz, zt0, ht0, hp0, Hbuf);
    k_logits<<<dim3(250), dim3(256), 0, stream>>>(Hbuf, Wout, lg);
    k_softmax<<<dim3(1), dim3(1024), 0, stream>>>(lg, out);
}

// Round 2
// 2043.870 us; speedup vs baseline: 1.0741x; 1.0741x over previous
//
#include <hip/hip_runtime.h>
#include <math.h>

#define TT  1024
#define DD  2048
#define NHH 2048
#define CC  1000

// ---------------------------------------------------------------------------
// GEMM: XH = x @ Wh^T ; XZ = x @ Wz^T + bz   (fp32, 64x64 tile, BK=32)
// grid (NHH/64, TT/64, 2); z=0 -> Wh/XH, z=1 -> Wz/XZ+bias
// ---------------------------------------------------------------------------
__global__ __launch_bounds__(256) void k_gemm(const float* __restrict__ X,
                                              const float* __restrict__ Wh,
                                              const float* __restrict__ Wz,
                                              const float* __restrict__ bz,
                                              float* __restrict__ XH,
                                              float* __restrict__ XZ) {
    __shared__ float As[32][68];   // [k][m]
    __shared__ float Bs[32][68];   // [k][n]
    const int z = blockIdx.z;
    const float* __restrict__ W = z ? Wz : Wh;
    float* __restrict__ OUT = z ? XZ : XH;
    const int n0 = blockIdx.x * 64;
    const int m0 = blockIdx.y * 64;
    const int tid = threadIdx.x;
    const int tx = tid & 15, ty = tid >> 4;
    const int lr = tid >> 2;           // 0..63 row within tile
    const int lc = (tid & 3) * 8;      // 0,8,16,24 col base

    float acc[4][4] = {};
    for (int k0 = 0; k0 < DD; k0 += 32) {
        float4 a0 = *(const float4*)&X[(size_t)(m0 + lr) * DD + k0 + lc];
        float4 a1 = *(const float4*)&X[(size_t)(m0 + lr) * DD + k0 + lc + 4];
        float4 b0 = *(const float4*)&W[(size_t)(n0 + lr) * DD + k0 + lc];
        float4 b1 = *(const float4*)&W[(size_t)(n0 + lr) * DD + k0 + lc + 4];
        As[lc+0][lr]=a0.x; As[lc+1][lr]=a0.y; As[lc+2][lr]=a0.z; As[lc+3][lr]=a0.w;
        As[lc+4][lr]=a1.x; As[lc+5][lr]=a1.y; As[lc+6][lr]=a1.z; As[lc+7][lr]=a1.w;
        Bs[lc+0][lr]=b0.x; Bs[lc+1][lr]=b0.y; Bs[lc+2][lr]=b0.z; Bs[lc+3][lr]=b0.w;
        Bs[lc+4][lr]=b1.x; Bs[lc+5][lr]=b1.y; Bs[lc+6][lr]=b1.z; Bs[lc+7][lr]=b1.w;
        __syncthreads();
#pragma unroll
        for (int kk = 0; kk < 32; ++kk) {
            float4 av = *(const float4*)&As[kk][ty * 4];
            float4 bv = *(const float4*)&Bs[kk][tx * 4];
            acc[0][0] = fmaf(av.x, bv.x, acc[0][0]); acc[0][1] = fmaf(av.x, bv.y, acc[0][1]);
            acc[0][2] = fmaf(av.x, bv.z, acc[0][2]); acc[0][3] = fmaf(av.x, bv.w, acc[0][3]);
            acc[1][0] = fmaf(av.y, bv.x, acc[1][0]); acc[1][1] = fmaf(av.y, bv.y, acc[1][1]);
            acc[1][2] = fmaf(av.y, bv.z, acc[1][2]); acc[1][3] = fmaf(av.y, bv.w, acc[1][3]);
            acc[2][0] = fmaf(av.z, bv.x, acc[2][0]); acc[2][1] = fmaf(av.z, bv.y, acc[2][1]);
            acc[2][2] = fmaf(av.z, bv.z, acc[2][2]); acc[2][3] = fmaf(av.z, bv.w, acc[2][3]);
            acc[3][0] = fmaf(av.w, bv.x, acc[3][0]); acc[3][1] = fmaf(av.w, bv.y, acc[3][1]);
            acc[3][2] = fmaf(av.w, bv.z, acc[3][2]); acc[3][3] = fmaf(av.w, bv.w, acc[3][3]);
        }
        __syncthreads();
    }
    float4 bias = make_float4(0.f, 0.f, 0.f, 0.f);
    if (z) bias = *(const float4*)&bz[n0 + tx * 4];
#pragma unroll
    for (int i = 0; i < 4; ++i) {
        float4 o = make_float4(acc[i][0] + bias.x, acc[i][1] + bias.y,
                               acc[i][2] + bias.z, acc[i][3] + bias.w);
        *(float4*)&OUT[(size_t)(m0 + ty * 4 + i) * NHH + n0 + tx * 4] = o;
    }
}

// ---------------------------------------------------------------------------
// Recurrent scan, software-pipelined to exploit the GRU's 1-step slack:
//   P_{t+1} = (1-z_t)*P_t + z_t*g_t,  z_t/g_t = f(U @ P_{t-1})
// Iteration t:  (i) ISSUE loads for epoch t (non-blocking)
//              (ii) matvec on P_{t-1} (resident in LDS)  <- hides (i)'s latency
//             (iii) gates (from P_{t-1} dots) + publish P_{t+1}
//              (iv) validate epoch-t tags (batched parallel retry) -> LDS
// 256 WGs (1/CU) x 256 thr; WG owns 8 h-elems; 16 U rows register-resident
// (128 f32/lane). 4-slot tagged (epoch<<32|f32bits) exchange buffer, relaxed
// agent-scope 64-bit atomics. Overwrite distance 4 > pipeline depth 2 => safe.
// __launch_bounds__(256,1): keep U in VGPRs (not AGPRs) — matvec is the chain.
// ---------------------------------------------------------------------------
__global__ __launch_bounds__(256, 1) void k_recur(
    const float* __restrict__ XH, const float* __restrict__ XZ,
    const float* __restrict__ Uh, const float* __restrict__ Uz,
    const float* __restrict__ zt0, const float* __restrict__ ht0,
    const float* __restrict__ hp0,
    unsigned long long* __restrict__ Hbuf) {
    __shared__ float Hs[NHH];
    __shared__ float dot_s[16];
    const int tid  = threadIdx.x;
    const int wave = tid >> 6, lane = tid & 63;
    const int base8 = blockIdx.x * 8;

    // load this wave's 4 U rows into registers
    const float* __restrict__ Um = (wave < 2) ? Uz : Uh;
    const int r0 = base8 + (wave & 1) * 4;
    float u[4][32];
#pragma unroll
    for (int r = 0; r < 4; ++r) {
        const float* __restrict__ row = Um + (size_t)(r0 + r) * NHH;
#pragma unroll
        for (int c = 0; c < 8; ++c) {
            float4 v = *(const float4*)&row[c * 256 + lane * 4];
            u[r][c*4+0] = v.x; u[r][c*4+1] = v.y; u[r][c*4+2] = v.z; u[r][c*4+3] = v.w;
        }
    }
    // Hs = P_0 = hprev0 (plain input, no tags needed for epoch 0)
#pragma unroll
    for (int k = 0; k < 8; ++k) Hs[k * 256 + tid] = hp0[k * 256 + tid];

    // own P_1 from initial gates; publish epoch 1
    float p_cur = 0.f;
    if (tid < 8) {
        float z0 = zt0[base8 + tid], g0 = ht0[base8 + tid], p0 = hp0[base8 + tid];
        p_cur = (1.0f - z0) * p0 + z0 * g0;
        unsigned long long pr = (1ull << 32) | (unsigned long long)__float_as_uint(p_cur);
        __hip_atomic_store(&Hbuf[(size_t)1 * NHH + base8 + tid], pr,
                           __ATOMIC_RELAXED, __HIP_MEMORY_SCOPE_AGENT);
    }
    __syncthreads();

    for (int t = 1; t < TT; ++t) {
        // (i) issue loads for epoch t; results not touched until (iv)
        const unsigned long long* __restrict__ src = Hbuf + (size_t)(t & 3) * NHH;
        unsigned long long pv[8];
#pragma unroll
        for (int k = 0; k < 8; ++k)
            pv[k] = __hip_atomic_load(&src[k * 256 + tid], __ATOMIC_RELAXED, __HIP_MEMORY_SCOPE_AGENT);
        float xzv = 0.f, xhv = 0.f;
        if (tid < 8) {
            xzv = XZ[(size_t)(t - 1) * NHH + base8 + tid];
            xhv = XH[(size_t)(t - 1) * NHH + base8 + tid];
        }
        // (ii) matvec: U @ P_{t-1} from LDS, 4 rows/wave, U in registers
        float a0 = 0.f, a1 = 0.f, a2 = 0.f, a3 = 0.f;
#pragma unroll
        for (int c = 0; c < 8; ++c) {
            float4 h4 = *(const float4*)&Hs[c * 256 + lane * 4];
            a0 = fmaf(u[0][c*4+0], h4.x, fmaf(u[0][c*4+1], h4.y, fmaf(u[0][c*4+2], h4.z, fmaf(u[0][c*4+3], h4.w, a0))));
            a1 = fmaf(u[1][c*4+0], h4.x, fmaf(u[1][c*4+1], h4.y, fmaf(u[1][c*4+2], h4.z, fmaf(u[1][c*4+3], h4.w, a1))));
            a2 = fmaf(u[2][c*4+0], h4.x, fmaf(u[2][c*4+1], h4.y, fmaf(u[2][c*4+2], h4.z, fmaf(u[2][c*4+3], h4.w, a2))));
            a3 = fmaf(u[3][c*4+0], h4.x, fmaf(u[3][c*4+1], h4.y, fmaf(u[3][c*4+2], h4.z, fmaf(u[3][c*4+3], h4.w, a3))));
        }
#pragma unroll
        for (int off = 32; off > 0; off >>= 1) {
            a0 += __shfl_xor(a0, off);
            a1 += __shfl_xor(a1, off);
            a2 += __shfl_xor(a2, off);
            a3 += __shfl_xor(a3, off);
        }
        if (lane == 0) {
            int di = ((wave & 1) * 4) + ((wave >> 1) * 8); // Uz -> 0..7, Uh -> 8..15
            dot_s[di + 0] = a0; dot_s[di + 1] = a1; dot_s[di + 2] = a2; dot_s[di + 3] = a3;
        }
        __syncthreads();
        // (iii) gates from P_{t-1} dots; P_{t+1} = (1-z)*P_t + z*g; publish
        if (tid < 8) {
            float z = 1.0f / (1.0f + expf(-(xzv + dot_s[tid])));
            float g = tanhf(xhv + dot_s[8 + tid]);
            float pn = (1.0f - z) * p_cur + z * g;
            p_cur = pn;
            unsigned long long pr = ((unsigned long long)(unsigned)(t + 1) << 32)
                                  | (unsigned long long)__float_as_uint(pn);
            __hip_atomic_store(&Hbuf[(size_t)((t + 1) & 3) * NHH + base8 + tid], pr,
                               __ATOMIC_RELAXED, __HIP_MEMORY_SCOPE_AGENT);
        }
        // (iv) validate epoch-t tags; batched parallel retry of stale ones
        for (;;) {
            unsigned stale = 0;
#pragma unroll
            for (int k = 0; k < 8; ++k)
                if ((unsigned)(pv[k] >> 32) != (unsigned)t) stale |= (1u << k);
            if (!stale) break;
#pragma unroll
            for (int k = 0; k < 8; ++k)
                if (stale & (1u << k))
                    pv[k] = __hip_atomic_load(&src[k * 256 + tid], __ATOMIC_RELAXED, __HIP_MEMORY_SCOPE_AGENT);
        }
#pragma unroll
        for (int k = 0; k < 8; ++k) Hs[k * 256 + tid] = __uint_as_float((unsigned)pv[k]);
        __syncthreads();
    }
}

// ---------------------------------------------------------------------------
// logits[r] = Wout[r,:] . P_1024   (epoch 1024 -> slot 0, value in low bits)
// ---------------------------------------------------------------------------
__global__ __launch_bounds__(256) void k_logits(const unsigned long long* __restrict__ Hbuf,
                                                const float* __restrict__ Wout,
                                                float* __restrict__ lg) {
    __shared__ float Hs[NHH];
    const int tid = threadIdx.x;
    for (int k = tid; k < NHH; k += 256) Hs[k] = __uint_as_float((unsigned)Hbuf[k]);
    __syncthreads();
    const int wave = tid >> 6, lane = tid & 63;
    const int row = blockIdx.x * 4 + wave;
    float a = 0.f;
#pragma unroll
    for (int c = 0; c < 8; ++c) {
        float4 w = *(const float4*)&Wout[(size_t)row * NHH + c * 256 + lane * 4];
        float4 h = *(const float4*)&Hs[c * 256 + lane * 4];
        a = fmaf(w.x, h.x, fmaf(w.y, h.y, fmaf(w.z, h.z, fmaf(w.w, h.w, a))));
    }
#pragma unroll
    for (int off = 32; off > 0; off >>= 1) a += __shfl_xor(a, off);
    if (lane == 0) lg[row] = a;
}

// ---------------------------------------------------------------------------
// softmax over 1000 logits, single block
// ---------------------------------------------------------------------------
__global__ __launch_bounds__(1024) void k_softmax(const float* __restrict__ lg,
                                                  float* __restrict__ out) {
    const int i = threadIdx.x;
    __shared__ float red[16];
    __shared__ float bc[2];
    float v = (i < CC) ? lg[i] : -3.0e38f;
    float m = v;
#pragma unroll
    for (int off = 32; off > 0; off >>= 1) m = fmaxf(m, __shfl_xor(m, off));
    if ((i & 63) == 0) red[i >> 6] = m;
    __syncthreads();
    if (i == 0) { float mm = red[0]; for (int k = 1; k < 16; ++k) mm = fmaxf(mm, red[k]); bc[0] = mm; }
    __syncthreads();
    float e = (i < CC) ? expf(v - bc[0]) : 0.f;
    float s = e;
#pragma unroll
    for (int off = 32; off > 0; off >>= 1) s += __shfl_xor(s, off);
    if ((i & 63) == 0) red[i >> 6] = s;
    __syncthreads();
    if (i == 0) { float ss = 0.f; for (int k = 0; k < 16; ++k) ss += red[k]; bc[1] = ss; }
    __syncthreads();
    if (i < CC) out[i] = e / bc[1];
}

extern "C" void kernel_launch(void* const* d_in, const int* in_sizes, int n_in,
                              void* d_out, int out_size, void* d_ws, size_t ws_size,
                              hipStream_t stream) {
    const float* x    = (const float*)d_in[0];
    const float* Wh   = (const float*)d_in[1];
    const float* Wz   = (const float*)d_in[2];
    // d_in[3] = Wr  (dead code in reference)
    const float* Uh   = (const float*)d_in[4];
    const float* Uz   = (const float*)d_in[5];
    const float* bz   = (const float*)d_in[6];
    // d_in[7] = Ur, d_in[8] = br (dead code)
    const float* Wout = (const float*)d_in[9];
    // d_in[10] = h0 (overwritten before first use since T>=1)
    const float* zt0  = (const float*)d_in[11];
    const float* ht0  = (const float*)d_in[12];
    const float* hp0  = (const float*)d_in[13];
    float* out = (float*)d_out;

    float* XH = (float*)d_ws;                                   // T*NH f32
    float* XZ = XH + (size_t)TT * NHH;                          // T*NH f32
    unsigned long long* Hbuf = (unsigned long long*)(XZ + (size_t)TT * NHH); // 4*NH u64
    float* lg = (float*)(Hbuf + 4 * NHH);                       // CC f32

    k_gemm<<<dim3(NHH / 64, TT / 64, 2), dim3(256), 0, stream>>>(x, Wh, Wz, bz, XH, XZ);
    k_recur<<<dim3(256), dim3(256), 0, stream>>>(XH, XZ, Uh, Uz, zt0, ht0, hp0, Hbuf);
    k_logits<<<dim3(250), dim3(256), 0, stream>>>(Hbuf, Wout, lg);
    k_softmax<<<dim3(1), dim3(1024), 0, stream>>>(lg, out);
}